// Round 9
// baseline (12238.834 us; speedup 1.0000x reference)
//
#include <hip/hip_runtime.h>

#define Bz   64
#define Tz   512
#define DIN  256
#define DOUT 1024
#define NWG  256
#define NTHR 512
#define HSTR 1028   // hls row stride: 1028 mod 32 = 4 -> rq rows 16 banks apart (2-way, free)
#define PSTR 272    // K-partial per-ks stride (>= 4*68; fixed in R7, keep)

// ---------------------------------------------------------------------------
// Pass 1: Z = x @ W_in + b_in -> written into d_out's ys region. (verified R1)
// ---------------------------------------------------------------------------
__global__ __launch_bounds__(256) void zgemm_kernel(
    const float* __restrict__ x, const float* __restrict__ Win,
    const float* __restrict__ bin, float* __restrict__ out)
{
    __shared__ float xT[32 * 132];
    __shared__ float ws[32 * 68];

    const int n0 = blockIdx.x * 128;
    const int c0 = blockIdx.y * 64;
    const int tid = threadIdx.x;
    const int tr = tid >> 4;
    const int tc = tid & 15;

    float acc[8][4];
#pragma unroll
    for (int i = 0; i < 8; ++i)
#pragma unroll
        for (int j = 0; j < 4; ++j) acc[i][j] = 0.f;

    for (int k0 = 0; k0 < DIN; k0 += 32) {
#pragma unroll
        for (int p = 0; p < 4; ++p) {
            int s = tid + p * 256;
            int r = s >> 3, kq = s & 7;
            float4 v = *(const float4*)(x + (size_t)(n0 + r) * DIN + k0 + kq * 4);
            xT[(kq * 4 + 0) * 132 + r] = v.x;
            xT[(kq * 4 + 1) * 132 + r] = v.y;
            xT[(kq * 4 + 2) * 132 + r] = v.z;
            xT[(kq * 4 + 3) * 132 + r] = v.w;
        }
#pragma unroll
        for (int p = 0; p < 2; ++p) {
            int s = tid + p * 256;
            int kk = s >> 4, cq = s & 15;
            *(float4*)(ws + kk * 68 + cq * 4) =
                *(const float4*)(Win + (size_t)(k0 + kk) * DOUT + c0 + cq * 4);
        }
        __syncthreads();
#pragma unroll
        for (int kk = 0; kk < 32; ++kk) {
            float4 a0 = *(const float4*)(xT + kk * 132 + tr * 4);
            float4 a1 = *(const float4*)(xT + kk * 132 + 64 + tr * 4);
            float4 b4 = *(const float4*)(ws + kk * 68 + tc * 4);
            float av[8] = {a0.x, a0.y, a0.z, a0.w, a1.x, a1.y, a1.z, a1.w};
            float bv[4] = {b4.x, b4.y, b4.z, b4.w};
#pragma unroll
            for (int i = 0; i < 8; ++i)
#pragma unroll
                for (int j = 0; j < 4; ++j)
                    acc[i][j] = fmaf(av[i], bv[j], acc[i][j]);
        }
        __syncthreads();
    }

    float4 bb = *(const float4*)(bin + c0 + tc * 4);
#pragma unroll
    for (int i = 0; i < 8; ++i) {
        int r = (i < 4) ? (tr * 4 + i) : (64 + tr * 4 + (i - 4));
        float4 o;
        o.x = acc[i][0] + bb.x;
        o.y = acc[i][1] + bb.y;
        o.z = acc[i][2] + bb.z;
        o.w = acc[i][3] + bb.w;
        *(float4*)(out + (size_t)(n0 + r) * DOUT + c0 + tc * 4) = o;
    }
}

// coherent (system-scope, cache-bypassing) 16B load
__device__ __forceinline__ float4 load_cf4(const float* p) {
    float4 v;
    asm volatile("global_load_dwordx4 %0, %1, off sc0 sc1"
                 : "=v"(v) : "v"(p) : "memory");
    return v;
}

// ---------------------------------------------------------------------------
// Pass 2a (primary): persistent cooperative kernel, ys-as-h.
// vs R7 (passed, 12.0ms, VALUBusy 5%, 3.7e8 bank conflicts):
//   1. grid.sync() -> per-row-group 64-wg flag barrier.
//   2. staging: 32 scalar system-atomics -> 8 coherent dwordx4 + one
//      plain "s_waitcnt vmcnt(0)" asm (volatile+memory-clobber ordering;
//      tied-operand form doesn't compile on gfx950 -- R8 lesson).
//   3. bank conflicts: HSTR=1028 (hls 2-way), Whs XOR swizzle (2-way).
// ---------------------------------------------------------------------------
__global__ __launch_bounds__(512, 1) void cwrnn_persistent(
    const float* __restrict__ Wh, const float* __restrict__ periods,
    const float* __restrict__ shifts, float* __restrict__ out,
    unsigned* __restrict__ flags)
{
    extern __shared__ float lds[];
    float* Whs = lds;            // [1024][16] swizzled, 16384 floats (64KB)
    float* hls = lds + 16384;    // [16][HSTR] = 16448 floats
    float* P   = hls;            // K-partials overlay (max idx 8699 < 16448)

    const int bid = blockIdx.x;
    const int tid = threadIdx.x;
    const int rg = bid >> 6;
    const int cg = bid & 63;
    const int r0 = rg * 16;
    const int c0 = cg * 16;

    // ---- load Wh slice once (swizzled store; same XOR used on read) ----
    {
        const int cq4 = tid & 3, kb = tid >> 2;   // kb 0..127
#pragma unroll
        for (int p = 0; p < 8; ++p) {
            int k = p * 128 + kb;
            int idx = (k * 16 + cq4 * 4) ^ (((k >> 2) & 3) << 3);
            *(float4*)(Whs + idx) =
                *(const float4*)(Wh + (size_t)k * DOUT + c0 + cq4 * 4);
        }
    }
    __syncthreads();

    // ---- roles ----
    const bool owner = (tid < 256);
    const int orow = tid >> 4;
    const int occ  = tid & 15;
    const int oc   = c0 + occ;
    float pm = 0.f, sm = 0.f;
    if (owner) { pm = periods[oc >> 7]; sm = shifts[oc >> 7]; }

    const int cq = tid & 3;           // 4 cols
    const int rq = (tid >> 2) & 3;    // 4 rows
    const int ks = tid >> 4;          // 32-way K split: k = p*128 + ks*4 + j
    const int swz = (ks & 3) << 3;    // Whs read swizzle key

    const int srow = tid >> 5;        // stage: 16 rows x 32 lanes
    const int skc  = tid & 31;

    for (int t = 0; t < Tz; ++t) {
        float zval = 0.f;
        const size_t zoff = (size_t)(r0 + orow) * ((size_t)Tz * DOUT)
                          + (size_t)t * DOUT + oc;
        if (owner) zval = out[zoff];   // sole reader/writer of this address

        float acc[4][4];
#pragma unroll
        for (int i = 0; i < 4; ++i)
#pragma unroll
            for (int j = 0; j < 4; ++j) acc[i][j] = 0.f;

        float hprev = 0.f;

        if (t > 0) {
            // ---- stage h = ys slice t-1: 8 coherent dwordx4 per thread ----
            {
                const float* src = out
                    + (size_t)(r0 + srow) * ((size_t)Tz * DOUT)
                    + (size_t)(t - 1) * DOUT + skc * 4;
                float4 v0 = load_cf4(src + 0 * 128);
                float4 v1 = load_cf4(src + 1 * 128);
                float4 v2 = load_cf4(src + 2 * 128);
                float4 v3 = load_cf4(src + 3 * 128);
                float4 v4 = load_cf4(src + 4 * 128);
                float4 v5 = load_cf4(src + 5 * 128);
                float4 v6 = load_cf4(src + 6 * 128);
                float4 v7 = load_cf4(src + 7 * 128);
                // volatile-asm ordering: the 8 loads above, then this wait,
                // then the LDS stores below (memory ops can't cross the
                // "memory" clobber). Tied-operand form is not supported.
                asm volatile("s_waitcnt vmcnt(0)" ::: "memory");
                float* dst = hls + srow * HSTR + skc * 4;
                *(float4*)(dst + 0 * 128) = v0;
                *(float4*)(dst + 1 * 128) = v1;
                *(float4*)(dst + 2 * 128) = v2;
                *(float4*)(dst + 3 * 128) = v3;
                *(float4*)(dst + 4 * 128) = v4;
                *(float4*)(dst + 5 * 128) = v5;
                *(float4*)(dst + 6 * 128) = v6;
                *(float4*)(dst + 7 * 128) = v7;
            }
            __syncthreads();

            // ---- GEMM: acc[i][j] += h[rq*4+i][k] * W[k][cq*4+j] ----
            {
                const float* h0 = hls + (rq * 4 + 0) * HSTR;
                const float* h1 = hls + (rq * 4 + 1) * HSTR;
                const float* h2 = hls + (rq * 4 + 2) * HSTR;
                const float* h3 = hls + (rq * 4 + 3) * HSTR;
#pragma unroll
                for (int p = 0; p < 8; ++p) {
                    const int kb = p * 128 + ks * 4;
                    float4 w0 = *(const float4*)(Whs + (((kb + 0) * 16 + cq * 4) ^ swz));
                    float4 w1 = *(const float4*)(Whs + (((kb + 1) * 16 + cq * 4) ^ swz));
                    float4 w2 = *(const float4*)(Whs + (((kb + 2) * 16 + cq * 4) ^ swz));
                    float4 w3 = *(const float4*)(Whs + (((kb + 3) * 16 + cq * 4) ^ swz));
                    float4 ha = *(const float4*)(h0 + kb);
                    float4 hb = *(const float4*)(h1 + kb);
                    float4 hc = *(const float4*)(h2 + kb);
                    float4 hd = *(const float4*)(h3 + kb);
                    float hv[4][4] = {
                        {ha.x, ha.y, ha.z, ha.w}, {hb.x, hb.y, hb.z, hb.w},
                        {hc.x, hc.y, hc.z, hc.w}, {hd.x, hd.y, hd.z, hd.w}};
                    float4 wv[4] = {w0, w1, w2, w3};
#pragma unroll
                    for (int j = 0; j < 4; ++j)
#pragma unroll
                        for (int i = 0; i < 4; ++i) {
                            acc[i][0] = fmaf(hv[i][j], wv[j].x, acc[i][0]);
                            acc[i][1] = fmaf(hv[i][j], wv[j].y, acc[i][1]);
                            acc[i][2] = fmaf(hv[i][j], wv[j].z, acc[i][2]);
                            acc[i][3] = fmaf(hv[i][j], wv[j].w, acc[i][3]);
                        }
                }
            }
            __syncthreads();
            if (owner) hprev = hls[orow * HSTR + oc];
            __syncthreads();
        }

        // ---- K-partials into P (overlay on hls) ----
        {
            float* pp = P + ks * PSTR + rq * 68 + cq * 4;
#pragma unroll
            for (int i = 0; i < 4; ++i) {
                pp[i * 16 + 0] = acc[i][0];
                pp[i * 16 + 1] = acc[i][1];
                pp[i * 16 + 2] = acc[i][2];
                pp[i * 16 + 3] = acc[i][3];
            }
        }
        __syncthreads();

        // ---- reduce + epilogue ----
        if (owner) {
            const float* pp = P + (orow >> 2) * 68 + (orow & 3) * 16 + occ;
            float sum = 0.f;
#pragma unroll
            for (int s = 0; s < 32; ++s) sum += pp[s * PSTR];
            float a = tanhf(zval + sum);
            float g = 0.5f * (sinf((float)t * pm + sm) + 1.0f);
            float y = (1.0f - g) * a + g * hprev;
            __hip_atomic_store(out + zoff, y, __ATOMIC_RELAXED,
                               __HIP_MEMORY_SCOPE_SYSTEM);   // ys[b,t,:] == h_{t+1}
            if (t == Tz - 1)
                out[(size_t)Bz * Tz * DOUT + (size_t)(r0 + orow) * DOUT + oc] = y;
        }

        // ---- per-row-group barrier (64 wgs), replaces grid.sync ----
        if (t != Tz - 1) {
            __syncthreads();   // all waves' y stores vmcnt-drained (coherent pt)
            const unsigned t1 = (unsigned)(t + 1);
            if (tid == 0)
                __hip_atomic_store(flags + (rg * 64 + cg) * 16, t1,
                                   __ATOMIC_RELEASE, __HIP_MEMORY_SCOPE_SYSTEM);
            if (tid < 64) {
                while (__hip_atomic_load(flags + (rg * 64 + tid) * 16,
                                         __ATOMIC_ACQUIRE,
                                         __HIP_MEMORY_SCOPE_SYSTEM) < t1)
                    __builtin_amdgcn_s_sleep(2);
            }
            __syncthreads();   // all 64 member flags observed by whole wg
        }
    }
}

// ---------------------------------------------------------------------------
// Pass 2b (fallback): R1's VERIFIED per-step kernel.
// ---------------------------------------------------------------------------
__device__ __forceinline__ int hswz(int r, int idx) {
    return idx ^ r ^ ((idx >> 4) & 48);
}

__global__ __launch_bounds__(256) void step_kernel(
    int t, const float* __restrict__ h_in, float* __restrict__ h_out,
    const float* __restrict__ Wh, const float* __restrict__ periods,
    const float* __restrict__ shifts, float* __restrict__ out)
{
    __shared__ float hs[16 * 1024];

    const int cg_ = blockIdx.x & 63;
    const int rg = blockIdx.x >> 6;
    const int c0 = cg_ * 16;
    const int r0 = rg * 16;
    const int tid = threadIdx.x;

    {
        const int row = tid >> 4;
        const int sb  = tid & 15;
#pragma unroll
        for (int i = 0; i < 16; ++i) {
            int s = sb + i * 16;
            float4 v = *(const float4*)(h_in + (size_t)(r0 + row) * DOUT + s * 4);
            int base = row * 1024;
            hs[base + hswz(row, s * 4 + 0)] = v.x;
            hs[base + hswz(row, s * 4 + 1)] = v.y;
            hs[base + hswz(row, s * 4 + 2)] = v.z;
            hs[base + hswz(row, s * 4 + 3)] = v.w;
        }
    }
    __syncthreads();

    const int cq   = tid & 3;
    const int half = (tid >> 2) & 3;
    const int r    = tid >> 4;
    const int c    = c0 + cq * 4;
    const int k0h  = half * 256;
    const float* wp = Wh + c;
    const float* hp = hs + r * 1024;

    float a0 = 0.f, a1 = 0.f, a2 = 0.f, a3 = 0.f;
#pragma unroll 16
    for (int k = 0; k < 256; ++k) {
        int kk = k0h + k;
        float4 w4 = *(const float4*)(wp + (size_t)kk * DOUT);
        float hv = hp[hswz(r, kk)];
        a0 = fmaf(hv, w4.x, a0);
        a1 = fmaf(hv, w4.y, a1);
        a2 = fmaf(hv, w4.z, a2);
        a3 = fmaf(hv, w4.w, a3);
    }
    a0 += __shfl_xor(a0, 4); a0 += __shfl_xor(a0, 8);
    a1 += __shfl_xor(a1, 4); a1 += __shfl_xor(a1, 8);
    a2 += __shfl_xor(a2, 4); a2 += __shfl_xor(a2, 8);
    a3 += __shfl_xor(a3, 4); a3 += __shfl_xor(a3, 8);

    if (half == 0) {
        const int m = c >> 7;
        const float g  = 0.5f * (sinf((float)t * periods[m] + shifts[m]) + 1.0f);
        const float og = 1.0f - g;

        const size_t zidx = (size_t)(r0 + r) * ((size_t)Tz * DOUT) + (size_t)t * DOUT + c;
        float4 z4 = *(const float4*)(out + zidx);
        float h0 = hp[hswz(r, c + 0)];
        float h1 = hp[hswz(r, c + 1)];
        float h2 = hp[hswz(r, c + 2)];
        float h3 = hp[hswz(r, c + 3)];
        float4 y;
        y.x = og * tanhf(z4.x + a0) + g * h0;
        y.y = og * tanhf(z4.y + a1) + g * h1;
        y.z = og * tanhf(z4.z + a2) + g * h2;
        y.w = og * tanhf(z4.w + a3) + g * h3;
        *(float4*)(out + zidx) = y;
        *(float4*)(h_out + (size_t)(r0 + r) * DOUT + c) = y;
        if (t == Tz - 1)
            *(float4*)(out + (size_t)Bz * Tz * DOUT + (size_t)(r0 + r) * DOUT + c) = y;
    }
}

// ---------------------------------------------------------------------------
extern "C" void kernel_launch(void* const* d_in, const int* in_sizes, int n_in,
                              void* d_out, int out_size, void* d_ws, size_t ws_size,
                              hipStream_t stream)
{
    const float* x   = (const float*)d_in[0];
    const float* Win = (const float*)d_in[1];
    const float* bin = (const float*)d_in[2];
    const float* Wh  = (const float*)d_in[3];
    const float* per = (const float*)d_in[4];
    const float* shf = (const float*)d_in[5];
    float* out = (float*)d_out;

    unsigned* flags = (unsigned*)d_ws;   // 256 * 16 u32 = 16 KB
    (void)hipMemsetAsync(flags, 0, 256 * 16 * sizeof(unsigned), stream);

    zgemm_kernel<<<dim3(256, 16), 256, 0, stream>>>(x, Win, bin, out);

    const int ldsBytes = (16384 + 16 * HSTR) * (int)sizeof(float);  // 131328 <= 160K

    bool coop_ok = false;
    hipError_t err = hipFuncSetAttribute((const void*)cwrnn_persistent,
                        hipFuncAttributeMaxDynamicSharedMemorySize, ldsBytes);
    if (err == hipSuccess) {
        void* args[] = { (void*)&Wh, (void*)&per, (void*)&shf, (void*)&out,
                         (void*)&flags };
        err = hipLaunchCooperativeKernel((const void*)cwrnn_persistent,
                                         dim3(NWG), dim3(NTHR), args,
                                         ldsBytes, stream);
        coop_ok = (err == hipSuccess);
    }

    if (!coop_ok) {
        // R1-verified fallback: per-step launches, ping-pong h in d_ws.
        float* ha = (float*)((char*)d_ws + 65536);
        float* hb = ha + (size_t)Bz * DOUT;
        (void)hipMemsetAsync(ha, 0, (size_t)Bz * DOUT * sizeof(float), stream);
        for (int t = 0; t < Tz; ++t) {
            step_kernel<<<256, 256, 0, stream>>>(t, ha, hb, Wh, per, shf, out);
            float* tmp = ha; ha = hb; hb = tmp;
        }
    }
}